// Round 1
// baseline (2935.846 us; speedup 1.0000x reference)
//
#include <hip/hip_runtime.h>

#define N_NODES 100000
#define N_EDGES 1000000
#define N_GRAPHS 128
#define IN_DIM 32
#define HID 64
#define LAT 32
#define N_LAYERS 3

#define MPAD 68  // padded LDS row stride (floats): 16B-aligned rows, breaks pow2 bank aliasing

// ---------------- input projection: h = x @ w_in + b_in ----------------
// one wave per node (64 lanes = 64 output features), w_in staged in LDS
__global__ __launch_bounds__(256) void proj_kernel(
    const float* __restrict__ x, const float* __restrict__ w_in,
    const float* __restrict__ b_in, float* __restrict__ h) {
    __shared__ float ws[IN_DIM * HID];   // 8 KB
    __shared__ float xs[4 * IN_DIM];     // 4 node rows
    int tid = threadIdx.x;
    for (int i = tid; i < IN_DIM * HID / 4; i += 256)
        ((float4*)ws)[i] = ((const float4*)w_in)[i];
    if (tid < 32) {
        int r = tid >> 3, c4 = tid & 7;
        int nn = blockIdx.x * 4 + r;
        float4 v = make_float4(0.f, 0.f, 0.f, 0.f);
        if (nn < N_NODES) v = ((const float4*)(x + (size_t)nn * IN_DIM))[c4];
        ((float4*)xs)[tid] = v;
    }
    __syncthreads();
    int w = tid >> 6, j = tid & 63;
    int n = blockIdx.x * 4 + w;
    if (n >= N_NODES) return;
    float acc = b_in[j];
#pragma unroll
    for (int k = 0; k < IN_DIM; k += 4) {
        float4 xv = *(const float4*)&xs[w * IN_DIM + k];
        acc += xv.x * ws[(k + 0) * HID + j];
        acc += xv.y * ws[(k + 1) * HID + j];
        acc += xv.z * ws[(k + 2) * HID + j];
        acc += xv.w * ws[(k + 3) * HID + j];
    }
    h[(size_t)n * HID + j] = acc;
}

// ---------------- edge scatter: agg[dst] += h[src] ----------------
// 16 threads per edge, float4 gather of the 256B source row, 4 f32 atomics each
__global__ __launch_bounds__(256) void scatter_kernel(
    const int* __restrict__ ei, const float* __restrict__ h,
    float* __restrict__ agg) {
    long long gid = (long long)blockIdx.x * 256 + threadIdx.x;
    int e = (int)(gid >> 4);
    if (e >= N_EDGES) return;
    int c = ((int)gid & 15) << 2;
    int s = ei[e];
    int d = ei[N_EDGES + e];
    float4 v = *(const float4*)(h + (size_t)s * HID + c);
    float* a = agg + (size_t)d * HID + c;
    atomicAdd(a + 0, v.x);
    atomicAdd(a + 1, v.y);
    atomicAdd(a + 2, v.z);
    atomicAdd(a + 3, v.w);
}

// ---------------- fused GIN MLP ----------------
// per block: 64-node tile. m = h+agg staged in LDS; t = relu(m@w1+b1) kept in
// LDS; h = relu(t@w2+b2) + h. 4x4 register micro-tiles, 16x16 thread grid.
__device__ __forceinline__ void gemm_tile(const float* __restrict__ a_lds,
                                          const float* __restrict__ w_lds,
                                          int r0, int c0, float acc[4][4]) {
#pragma unroll
    for (int i = 0; i < 4; i++)
#pragma unroll
        for (int j = 0; j < 4; j++) acc[i][j] = 0.f;
#pragma unroll
    for (int k0 = 0; k0 < HID; k0 += 4) {
        float4 av0 = *(const float4*)&a_lds[(r0 + 0) * MPAD + k0];
        float4 av1 = *(const float4*)&a_lds[(r0 + 1) * MPAD + k0];
        float4 av2 = *(const float4*)&a_lds[(r0 + 2) * MPAD + k0];
        float4 av3 = *(const float4*)&a_lds[(r0 + 3) * MPAD + k0];
        float4 wv0 = *(const float4*)&w_lds[(k0 + 0) * HID + c0];
        float4 wv1 = *(const float4*)&w_lds[(k0 + 1) * HID + c0];
        float4 wv2 = *(const float4*)&w_lds[(k0 + 2) * HID + c0];
        float4 wv3 = *(const float4*)&w_lds[(k0 + 3) * HID + c0];
        float a[4][4] = {{av0.x, av0.y, av0.z, av0.w},
                         {av1.x, av1.y, av1.z, av1.w},
                         {av2.x, av2.y, av2.z, av2.w},
                         {av3.x, av3.y, av3.z, av3.w}};
        float wm[4][4] = {{wv0.x, wv0.y, wv0.z, wv0.w},
                          {wv1.x, wv1.y, wv1.z, wv1.w},
                          {wv2.x, wv2.y, wv2.z, wv2.w},
                          {wv3.x, wv3.y, wv3.z, wv3.w}};
#pragma unroll
        for (int i = 0; i < 4; i++)
#pragma unroll
            for (int kk = 0; kk < 4; kk++) {
                acc[i][0] += a[i][kk] * wm[kk][0];
                acc[i][1] += a[i][kk] * wm[kk][1];
                acc[i][2] += a[i][kk] * wm[kk][2];
                acc[i][3] += a[i][kk] * wm[kk][3];
            }
    }
}

__global__ __launch_bounds__(256) void mlp_kernel(
    float* __restrict__ h, const float* __restrict__ agg,
    const float* __restrict__ w1, const float* __restrict__ b1,
    const float* __restrict__ w2, const float* __restrict__ b2) {
    __shared__ float w1s[HID * HID];   // 16 KB
    __shared__ float w2s[HID * HID];   // 16 KB
    __shared__ float ms[64 * MPAD];    // 17 KB, reused for t
    int tid = threadIdx.x;
    int row0 = blockIdx.x * 64;
    for (int i = tid; i < HID * HID / 4; i += 256) {
        ((float4*)w1s)[i] = ((const float4*)w1)[i];
        ((float4*)w2s)[i] = ((const float4*)w2)[i];
    }
#pragma unroll
    for (int i = 0; i < 4; i++) {
        int f = tid + i * 256;
        int r = f >> 4, c4 = f & 15;
        int n = row0 + r;
        float4 mv = make_float4(0.f, 0.f, 0.f, 0.f);
        if (n < N_NODES) {
            float4 h4 = ((const float4*)(h + (size_t)n * HID))[c4];
            float4 a4 = ((const float4*)(agg + (size_t)n * HID))[c4];
            mv = make_float4(h4.x + a4.x, h4.y + a4.y, h4.z + a4.z, h4.w + a4.w);
        }
        *(float4*)&ms[r * MPAD + c4 * 4] = mv;
    }
    __syncthreads();

    int ty = tid >> 4, tx = tid & 15;
    int r0 = ty * 4, c0 = tx * 4;

    float acc[4][4];
    gemm_tile(ms, w1s, r0, c0, acc);  // GEMM1

    float bv1[4] = {b1[c0 + 0], b1[c0 + 1], b1[c0 + 2], b1[c0 + 3]};
    float t[4][4];
#pragma unroll
    for (int i = 0; i < 4; i++)
#pragma unroll
        for (int j = 0; j < 4; j++) t[i][j] = fmaxf(acc[i][j] + bv1[j], 0.f);

    __syncthreads();  // all GEMM1 reads of ms complete
#pragma unroll
    for (int i = 0; i < 4; i++)
        *(float4*)&ms[(r0 + i) * MPAD + c0] =
            make_float4(t[i][0], t[i][1], t[i][2], t[i][3]);
    __syncthreads();

    gemm_tile(ms, w2s, r0, c0, acc);  // GEMM2

    float bv2[4] = {b2[c0 + 0], b2[c0 + 1], b2[c0 + 2], b2[c0 + 3]};
#pragma unroll
    for (int i = 0; i < 4; i++) {
        int n = row0 + r0 + i;
        if (n < N_NODES) {
            float4 hold = *(const float4*)(h + (size_t)n * HID + c0);
            float4 o;
            o.x = fmaxf(acc[i][0] + bv2[0], 0.f) + hold.x;
            o.y = fmaxf(acc[i][1] + bv2[1], 0.f) + hold.y;
            o.z = fmaxf(acc[i][2] + bv2[2], 0.f) + hold.z;
            o.w = fmaxf(acc[i][3] + bv2[3], 0.f) + hold.w;
            *(float4*)(h + (size_t)n * HID + c0) = o;
        }
    }
}

// ---------------- global add pool (batch is sorted -> run-length reduce) ----
__global__ __launch_bounds__(256) void pool_kernel(
    const float* __restrict__ h, const int* __restrict__ batch,
    float* __restrict__ pooled) {
    int tid = threadIdx.x;
    int w = tid >> 6, j = tid & 63;
    int n0 = blockIdx.x * 256 + w * 64;
    if (n0 >= N_NODES) return;
    int nend = min(n0 + 64, N_NODES);
    float acc = 0.f;
    int cur = batch[n0];
    for (int n = n0; n < nend; n++) {
        int b = batch[n];
        if (b != cur) {  // wave-uniform branch
            atomicAdd(&pooled[cur * HID + j], acc);
            acc = 0.f;
            cur = b;
        }
        acc += h[(size_t)n * HID + j];
    }
    atomicAdd(&pooled[cur * HID + j], acc);
}

// ---------------- final FC: out = pooled @ w_fc + b_fc ----------------
__global__ __launch_bounds__(256) void final_kernel(
    const float* __restrict__ pooled, const float* __restrict__ w_fc,
    const float* __restrict__ b_fc, float* __restrict__ out) {
    int gid = blockIdx.x * 256 + threadIdx.x;
    if (gid >= N_GRAPHS * LAT) return;
    int g = gid >> 5, j = gid & 31;
    float acc = b_fc[j];
#pragma unroll
    for (int k = 0; k < HID; k++)
        acc += pooled[g * HID + k] * w_fc[k * LAT + j];
    out[gid] = acc;
}

extern "C" void kernel_launch(void* const* d_in, const int* in_sizes, int n_in,
                              void* d_out, int out_size, void* d_ws,
                              size_t ws_size, hipStream_t stream) {
    const float* x    = (const float*)d_in[0];
    const int*   ei   = (const int*)d_in[1];    // [2, 1M] int32
    const int*   batch= (const int*)d_in[2];    // [100k] int32, sorted
    const float* w_in = (const float*)d_in[3];
    const float* b_in = (const float*)d_in[4];
    const float* w1   = (const float*)d_in[5];  // [3,64,64]
    const float* b1   = (const float*)d_in[6];  // [3,64]
    const float* w2   = (const float*)d_in[7];
    const float* b2   = (const float*)d_in[8];
    const float* w_fc = (const float*)d_in[9];
    const float* b_fc = (const float*)d_in[10];
    float* out = (float*)d_out;

    // workspace: h (25.6MB) | agg (25.6MB) | pooled (32KB)  -> ~51.3MB
    float* h      = (float*)d_ws;
    float* agg    = h + (size_t)N_NODES * HID;
    float* pooled = agg + (size_t)N_NODES * HID;

    proj_kernel<<<(N_NODES + 3) / 4, 256, 0, stream>>>(x, w_in, b_in, h);

    for (int i = 0; i < N_LAYERS; i++) {
        hipMemsetAsync(agg, 0, (size_t)N_NODES * HID * sizeof(float), stream);
        scatter_kernel<<<(N_EDGES * 16) / 256, 256, 0, stream>>>(ei, h, agg);
        mlp_kernel<<<(N_NODES + 63) / 64, 256, 0, stream>>>(
            h, agg, w1 + (size_t)i * HID * HID, b1 + (size_t)i * HID,
            w2 + (size_t)i * HID * HID, b2 + (size_t)i * HID);
    }

    hipMemsetAsync(pooled, 0, N_GRAPHS * HID * sizeof(float), stream);
    pool_kernel<<<(N_NODES + 255) / 256, 256, 0, stream>>>(h, batch, pooled);
    final_kernel<<<(N_GRAPHS * LAT + 255) / 256, 256, 0, stream>>>(
        pooled, w_fc, b_fc, out);
}

// Round 2
// 622.453 us; speedup vs baseline: 4.7166x; 4.7166x over previous
//
#include <hip/hip_runtime.h>

#define N_NODES 100000
#define N_EDGES 1000000
#define N_GRAPHS 128
#define IN_DIM 32
#define HID 64
#define LAT 32
#define N_LAYERS 3

#define MPAD 68  // padded LDS row stride (floats)
#define NB_SUM ((N_NODES + 255) / 256)  // 391 scan blocks

// ---------------- input projection: h = x @ w_in + b_in ----------------
__global__ __launch_bounds__(256) void proj_kernel(
    const float* __restrict__ x, const float* __restrict__ w_in,
    const float* __restrict__ b_in, float* __restrict__ h) {
    __shared__ float ws[IN_DIM * HID];   // 8 KB
    __shared__ float xs[4 * IN_DIM];
    int tid = threadIdx.x;
    for (int i = tid; i < IN_DIM * HID / 4; i += 256)
        ((float4*)ws)[i] = ((const float4*)w_in)[i];
    if (tid < 32) {
        int r = tid >> 3, c4 = tid & 7;
        int nn = blockIdx.x * 4 + r;
        float4 v = make_float4(0.f, 0.f, 0.f, 0.f);
        if (nn < N_NODES) v = ((const float4*)(x + (size_t)nn * IN_DIM))[c4];
        ((float4*)xs)[tid] = v;
    }
    __syncthreads();
    int w = tid >> 6, j = tid & 63;
    int n = blockIdx.x * 4 + w;
    if (n >= N_NODES) return;
    float acc = b_in[j];
#pragma unroll
    for (int k = 0; k < IN_DIM; k += 4) {
        float4 xv = *(const float4*)&xs[w * IN_DIM + k];
        acc += xv.x * ws[(k + 0) * HID + j];
        acc += xv.y * ws[(k + 1) * HID + j];
        acc += xv.z * ws[(k + 2) * HID + j];
        acc += xv.w * ws[(k + 3) * HID + j];
    }
    h[(size_t)n * HID + j] = acc;
}

// ---------------- CSR build ----------------
__global__ __launch_bounds__(256) void hist_kernel(const int* __restrict__ ei,
                                                   int* __restrict__ counts) {
    int e = blockIdx.x * 256 + threadIdx.x;
    if (e < N_EDGES) atomicAdd(&counts[ei[N_EDGES + e]], 1);
}

__global__ __launch_bounds__(256) void block_sum_kernel(
    const int* __restrict__ counts, int* __restrict__ bsums) {
    __shared__ int sd[4];
    int i = blockIdx.x * 256 + threadIdx.x;
    int v = (i < N_NODES) ? counts[i] : 0;
#pragma unroll
    for (int off = 32; off >= 1; off >>= 1) v += __shfl_down(v, off);
    int lane = threadIdx.x & 63, w = threadIdx.x >> 6;
    if (lane == 0) sd[w] = v;
    __syncthreads();
    if (threadIdx.x == 0) bsums[blockIdx.x] = sd[0] + sd[1] + sd[2] + sd[3];
}

__global__ __launch_bounds__(256) void scan_bsums_kernel(
    const int* __restrict__ bsums, int* __restrict__ bofs, int nb) {
    __shared__ int tmp[256];
    __shared__ int carry;
    int tid = threadIdx.x;
    if (tid == 0) carry = 0;
    __syncthreads();
    for (int base = 0; base < nb; base += 256) {
        int v = (base + tid < nb) ? bsums[base + tid] : 0;
        tmp[tid] = v;
        __syncthreads();
        for (int off = 1; off < 256; off <<= 1) {
            int t = (tid >= off) ? tmp[tid - off] : 0;
            __syncthreads();
            tmp[tid] += t;
            __syncthreads();
        }
        if (base + tid < nb) bofs[base + tid] = carry + tmp[tid] - v;
        __syncthreads();
        if (tid == 255) carry += tmp[255];
        __syncthreads();
    }
}

__global__ __launch_bounds__(256) void offsets_kernel(
    const int* __restrict__ counts, const int* __restrict__ bofs,
    int* __restrict__ offsets, int* __restrict__ cursor) {
    __shared__ int tmp[256];
    int tid = threadIdx.x;
    int i = blockIdx.x * 256 + tid;
    int v = (i < N_NODES) ? counts[i] : 0;
    tmp[tid] = v;
    __syncthreads();
    for (int off = 1; off < 256; off <<= 1) {
        int t = (tid >= off) ? tmp[tid - off] : 0;
        __syncthreads();
        tmp[tid] += t;
        __syncthreads();
    }
    int excl = tmp[tid] - v + bofs[blockIdx.x];
    if (i < N_NODES) {
        offsets[i] = excl;
        cursor[i] = excl;
        if (i == N_NODES - 1) offsets[N_NODES] = excl + v;
    }
}

__global__ __launch_bounds__(256) void fill_kernel(const int* __restrict__ ei,
                                                   int* __restrict__ cursor,
                                                   int* __restrict__ srcs) {
    int e = blockIdx.x * 256 + threadIdx.x;
    if (e < N_EDGES) {
        int d = ei[N_EDGES + e];
        int p = atomicAdd(&cursor[d], 1);
        srcs[p] = ei[e];
    }
}

// ---------------- gather: agg[n] = sum_{e in in(n)} h[src[e]] ----------------
// one wave per node; lane j owns feature j; edge ids loaded coalesced, shfl-broadcast
__global__ __launch_bounds__(256) void gather_kernel(
    const int* __restrict__ offsets, const int* __restrict__ srcs,
    const float* __restrict__ h, float* __restrict__ agg) {
    int w = threadIdx.x >> 6, j = threadIdx.x & 63;
    int n = blockIdx.x * 4 + w;
    if (n >= N_NODES) return;
    int beg = offsets[n], end = offsets[n + 1];
    float acc0 = 0.f, acc1 = 0.f;
    for (int c = beg; c < end; c += 64) {
        int myS = (c + j < end) ? srcs[c + j] : 0;
        int m = min(64, end - c);
        int i = 0;
        for (; i + 1 < m; i += 2) {
            int s0 = __shfl(myS, i);
            int s1 = __shfl(myS, i + 1);
            acc0 += h[(size_t)s0 * HID + j];
            acc1 += h[(size_t)s1 * HID + j];
        }
        if (i < m) {
            int s0 = __shfl(myS, i);
            acc0 += h[(size_t)s0 * HID + j];
        }
    }
    agg[(size_t)n * HID + j] = acc0 + acc1;
}

// ---------------- fused GIN MLP ----------------
__device__ __forceinline__ void gemm_tile(const float* __restrict__ a_lds,
                                          const float* __restrict__ w_lds,
                                          int r0, int c0, float acc[4][4]) {
#pragma unroll
    for (int i = 0; i < 4; i++)
#pragma unroll
        for (int j = 0; j < 4; j++) acc[i][j] = 0.f;
#pragma unroll
    for (int k0 = 0; k0 < HID; k0 += 4) {
        float4 av0 = *(const float4*)&a_lds[(r0 + 0) * MPAD + k0];
        float4 av1 = *(const float4*)&a_lds[(r0 + 1) * MPAD + k0];
        float4 av2 = *(const float4*)&a_lds[(r0 + 2) * MPAD + k0];
        float4 av3 = *(const float4*)&a_lds[(r0 + 3) * MPAD + k0];
        float4 wv0 = *(const float4*)&w_lds[(k0 + 0) * HID + c0];
        float4 wv1 = *(const float4*)&w_lds[(k0 + 1) * HID + c0];
        float4 wv2 = *(const float4*)&w_lds[(k0 + 2) * HID + c0];
        float4 wv3 = *(const float4*)&w_lds[(k0 + 3) * HID + c0];
        float a[4][4] = {{av0.x, av0.y, av0.z, av0.w},
                         {av1.x, av1.y, av1.z, av1.w},
                         {av2.x, av2.y, av2.z, av2.w},
                         {av3.x, av3.y, av3.z, av3.w}};
        float wm[4][4] = {{wv0.x, wv0.y, wv0.z, wv0.w},
                          {wv1.x, wv1.y, wv1.z, wv1.w},
                          {wv2.x, wv2.y, wv2.z, wv2.w},
                          {wv3.x, wv3.y, wv3.z, wv3.w}};
#pragma unroll
        for (int i = 0; i < 4; i++)
#pragma unroll
            for (int kk = 0; kk < 4; kk++) {
                acc[i][0] += a[i][kk] * wm[kk][0];
                acc[i][1] += a[i][kk] * wm[kk][1];
                acc[i][2] += a[i][kk] * wm[kk][2];
                acc[i][3] += a[i][kk] * wm[kk][3];
            }
    }
}

__global__ __launch_bounds__(256) void mlp_kernel(
    float* __restrict__ h, const float* __restrict__ agg,
    const float* __restrict__ w1, const float* __restrict__ b1,
    const float* __restrict__ w2, const float* __restrict__ b2) {
    __shared__ float w1s[HID * HID];
    __shared__ float w2s[HID * HID];
    __shared__ float ms[64 * MPAD];
    int tid = threadIdx.x;
    int row0 = blockIdx.x * 64;
    for (int i = tid; i < HID * HID / 4; i += 256) {
        ((float4*)w1s)[i] = ((const float4*)w1)[i];
        ((float4*)w2s)[i] = ((const float4*)w2)[i];
    }
#pragma unroll
    for (int i = 0; i < 4; i++) {
        int f = tid + i * 256;
        int r = f >> 4, c4 = f & 15;
        int n = row0 + r;
        float4 mv = make_float4(0.f, 0.f, 0.f, 0.f);
        if (n < N_NODES) {
            float4 h4 = ((const float4*)(h + (size_t)n * HID))[c4];
            float4 a4 = ((const float4*)(agg + (size_t)n * HID))[c4];
            mv = make_float4(h4.x + a4.x, h4.y + a4.y, h4.z + a4.z, h4.w + a4.w);
        }
        *(float4*)&ms[r * MPAD + c4 * 4] = mv;
    }
    __syncthreads();

    int ty = tid >> 4, tx = tid & 15;
    int r0 = ty * 4, c0 = tx * 4;

    float acc[4][4];
    gemm_tile(ms, w1s, r0, c0, acc);

    float bv1[4] = {b1[c0 + 0], b1[c0 + 1], b1[c0 + 2], b1[c0 + 3]};
    float t[4][4];
#pragma unroll
    for (int i = 0; i < 4; i++)
#pragma unroll
        for (int j = 0; j < 4; j++) t[i][j] = fmaxf(acc[i][j] + bv1[j], 0.f);

    __syncthreads();
#pragma unroll
    for (int i = 0; i < 4; i++)
        *(float4*)&ms[(r0 + i) * MPAD + c0] =
            make_float4(t[i][0], t[i][1], t[i][2], t[i][3]);
    __syncthreads();

    gemm_tile(ms, w2s, r0, c0, acc);

    float bv2[4] = {b2[c0 + 0], b2[c0 + 1], b2[c0 + 2], b2[c0 + 3]};
#pragma unroll
    for (int i = 0; i < 4; i++) {
        int n = row0 + r0 + i;
        if (n < N_NODES) {
            float4 hold = *(const float4*)(h + (size_t)n * HID + c0);
            float4 o;
            o.x = fmaxf(acc[i][0] + bv2[0], 0.f) + hold.x;
            o.y = fmaxf(acc[i][1] + bv2[1], 0.f) + hold.y;
            o.z = fmaxf(acc[i][2] + bv2[2], 0.f) + hold.z;
            o.w = fmaxf(acc[i][3] + bv2[3], 0.f) + hold.w;
            *(float4*)(h + (size_t)n * HID + c0) = o;
        }
    }
}

// ---------------- global add pool ----------------
__global__ __launch_bounds__(256) void pool_kernel(
    const float* __restrict__ h, const int* __restrict__ batch,
    float* __restrict__ pooled) {
    int tid = threadIdx.x;
    int w = tid >> 6, j = tid & 63;
    int n0 = blockIdx.x * 256 + w * 64;
    if (n0 >= N_NODES) return;
    int nend = min(n0 + 64, N_NODES);
    float acc = 0.f;
    int cur = batch[n0];
    for (int n = n0; n < nend; n++) {
        int b = batch[n];
        if (b != cur) {
            atomicAdd(&pooled[cur * HID + j], acc);
            acc = 0.f;
            cur = b;
        }
        acc += h[(size_t)n * HID + j];
    }
    atomicAdd(&pooled[cur * HID + j], acc);
}

// ---------------- final FC ----------------
__global__ __launch_bounds__(256) void final_kernel(
    const float* __restrict__ pooled, const float* __restrict__ w_fc,
    const float* __restrict__ b_fc, float* __restrict__ out) {
    int gid = blockIdx.x * 256 + threadIdx.x;
    if (gid >= N_GRAPHS * LAT) return;
    int g = gid >> 5, j = gid & 31;
    float acc = b_fc[j];
#pragma unroll
    for (int k = 0; k < HID; k++)
        acc += pooled[g * HID + k] * w_fc[k * LAT + j];
    out[gid] = acc;
}

extern "C" void kernel_launch(void* const* d_in, const int* in_sizes, int n_in,
                              void* d_out, int out_size, void* d_ws,
                              size_t ws_size, hipStream_t stream) {
    const float* x     = (const float*)d_in[0];
    const int*   ei    = (const int*)d_in[1];
    const int*   batch = (const int*)d_in[2];
    const float* w_in  = (const float*)d_in[3];
    const float* b_in  = (const float*)d_in[4];
    const float* w1    = (const float*)d_in[5];
    const float* b1    = (const float*)d_in[6];
    const float* w2    = (const float*)d_in[7];
    const float* b2    = (const float*)d_in[8];
    const float* w_fc  = (const float*)d_in[9];
    const float* b_fc  = (const float*)d_in[10];
    float* out = (float*)d_out;

    // persistent: h | agg | pooled | offsets | srcs   (~56 MB)
    float* h       = (float*)d_ws;
    float* agg     = h + (size_t)N_NODES * HID;
    float* pooled  = agg + (size_t)N_NODES * HID;
    int*   offsets = (int*)(pooled + N_GRAPHS * HID);   // N_NODES+1
    int*   srcs    = offsets + (N_NODES + 2);           // N_EDGES
    // build-time arrays overlaid into agg's region (dead before first gather)
    int* counts = (int*)agg;            // N_NODES
    int* cursor = counts + N_NODES;     // N_NODES
    int* bsums  = cursor + N_NODES;     // NB_SUM
    int* bofs   = bsums + (NB_SUM + 1); // NB_SUM

    proj_kernel<<<(N_NODES + 3) / 4, 256, 0, stream>>>(x, w_in, b_in, h);

    // CSR build (once; edges constant across layers)
    hipMemsetAsync(counts, 0, N_NODES * sizeof(int), stream);
    hist_kernel<<<(N_EDGES + 255) / 256, 256, 0, stream>>>(ei, counts);
    block_sum_kernel<<<NB_SUM, 256, 0, stream>>>(counts, bsums);
    scan_bsums_kernel<<<1, 256, 0, stream>>>(bsums, bofs, NB_SUM);
    offsets_kernel<<<NB_SUM, 256, 0, stream>>>(counts, bofs, offsets, cursor);
    fill_kernel<<<(N_EDGES + 255) / 256, 256, 0, stream>>>(ei, cursor, srcs);

    for (int i = 0; i < N_LAYERS; i++) {
        gather_kernel<<<(N_NODES + 3) / 4, 256, 0, stream>>>(offsets, srcs, h, agg);
        mlp_kernel<<<(N_NODES + 63) / 64, 256, 0, stream>>>(
            h, agg, w1 + (size_t)i * HID * HID, b1 + (size_t)i * HID,
            w2 + (size_t)i * HID * HID, b2 + (size_t)i * HID);
    }

    hipMemsetAsync(pooled, 0, N_GRAPHS * HID * sizeof(float), stream);
    pool_kernel<<<(N_NODES + 255) / 256, 256, 0, stream>>>(h, batch, pooled);
    final_kernel<<<(N_GRAPHS * LAT + 255) / 256, 256, 0, stream>>>(
        pooled, w_fc, b_fc, out);
}